// Round 11
// baseline (486.407 us; speedup 1.0000x reference)
//
#include <hip/hip_runtime.h>

// 3D SpatialTransformer (grid_sample, align_corners=True, zero padding).
// B=2, C=3, S=160, fp32. One thread per (b, spatial) site, all 3 channels.

constexpr int S  = 160;
constexpr long long S3 = (long long)S * S * S;   // 4,096,000
constexpr int BATCH = 2;
constexpr int CH = 3;

__global__ __launch_bounds__(256) void st3d_kernel(
    const float* __restrict__ src,
    const float* __restrict__ flow,
    const int*   __restrict__ is_msk,
    float*       __restrict__ out)
{
    long long tid = (long long)blockIdx.x * blockDim.x + threadIdx.x;
    if (tid >= BATCH * S3) return;
    int b = (int)(tid / S3);
    int s = (int)(tid % S3);
    int w = s % S;
    int t = s / S;
    int h = t % S;
    int d = t / S;

    const float* fb = flow + (size_t)b * 3 * S3;
    float z = (float)d + fb[s];
    float y = (float)h + fb[S3 + s];
    float x = (float)w + fb[2 * S3 + s];

    const float* sb = src + (size_t)b * CH * S3;
    float r0 = 0.f, r1 = 0.f, r2 = 0.f;

    if (__builtin_expect(*is_msk != 0, 0)) {
        // nearest: round-half-to-even == rintf (default RNE mode)
        int iz = (int)rintf(z), iy = (int)rintf(y), ix = (int)rintf(x);
        bool v = (unsigned)iz < (unsigned)S && (unsigned)iy < (unsigned)S &&
                 (unsigned)ix < (unsigned)S;
        int izc = min(max(iz, 0), S - 1);
        int iyc = min(max(iy, 0), S - 1);
        int ixc = min(max(ix, 0), S - 1);
        int idx = (izc * S + iyc) * S + ixc;
        float m = v ? 1.f : 0.f;
        r0 = m * sb[idx];
        r1 = m * sb[S3 + idx];
        r2 = m * sb[2 * S3 + idx];
    } else {
        // trilinear, zero padding. Same corner order as reference:
        // (z0,z1) outer, (y0,y1), (x0,x1) inner — identical fp accumulation.
        float zf = floorf(z), yf = floorf(y), xf = floorf(x);
        float tz = z - zf, ty = y - yf, tx = x - xf;
        int z0 = (int)zf, y0 = (int)yf, x0 = (int)xf;
        float wz_[2] = {1.f - tz, tz};
        float wy_[2] = {1.f - ty, ty};
        float wx_[2] = {1.f - tx, tx};
        #pragma unroll
        for (int dz = 0; dz < 2; ++dz) {
            int iz = z0 + dz;
            bool vz = (unsigned)iz < (unsigned)S;
            int izc = min(max(iz, 0), S - 1);
            #pragma unroll
            for (int dy = 0; dy < 2; ++dy) {
                int iy = y0 + dy;
                bool vy = vz && ((unsigned)iy < (unsigned)S);
                int iyc = min(max(iy, 0), S - 1);
                #pragma unroll
                for (int dx = 0; dx < 2; ++dx) {
                    int ix = x0 + dx;
                    bool v = vy && ((unsigned)ix < (unsigned)S);
                    int ixc = min(max(ix, 0), S - 1);
                    int idx = (izc * S + iyc) * S + ixc;
                    float wgt = v ? wz_[dz] * wy_[dy] * wx_[dx] : 0.f;
                    r0 += wgt * sb[idx];
                    r1 += wgt * sb[S3 + idx];
                    r2 += wgt * sb[2 * S3 + idx];
                }
            }
        }
    }

    float* ob = out + (size_t)b * CH * S3;
    ob[s]          = r0;
    ob[S3 + s]     = r1;
    ob[2 * S3 + s] = r2;
}

extern "C" void kernel_launch(void* const* d_in, const int* in_sizes, int n_in,
                              void* d_out, int out_size, void* d_ws, size_t ws_size,
                              hipStream_t stream) {
    const float* src    = (const float*)d_in[0];
    const float* flow   = (const float*)d_in[1];
    const int*   is_msk = (const int*)d_in[2];
    float*       out    = (float*)d_out;

    long long total = (long long)BATCH * S3;   // 8,192,000
    int block = 256;
    int grid  = (int)((total + block - 1) / block);  // 32,000
    st3d_kernel<<<grid, block, 0, stream>>>(src, flow, is_msk, out);
}

// Round 13
// 434.823 us; speedup vs baseline: 1.1186x; 1.1186x over previous
//
#include <hip/hip_runtime.h>

// 3D SpatialTransformer (grid_sample, align_corners=True, zero padding).
// B=2, C=3, S=160, fp32. One thread per (b,spatial) site, all 3 channels.
// R12: pairwise x-gathers (dwordx2) + bijective XCD-chunked block swizzle.

constexpr int S   = 160;
constexpr int S3I = S * S * S;            // 4,096,000 (fits int)
constexpr int BATCH = 2;
constexpr int CH  = 3;
constexpr int BLOCKS = (BATCH * S3I) / 256;  // 32,000 exact
constexpr int NXCD = 8;

struct F2 { float a, b; };   // align 4; backend merges to dwordx2 iff legal

__global__ __launch_bounds__(256) void st3d_kernel(
    const float* __restrict__ src,
    const float* __restrict__ flow,
    const int*   __restrict__ is_msk,
    float*       __restrict__ out)
{
    // bijective XCD-chunked swizzle (BLOCKS % NXCD == 0): each XCD owns a
    // contiguous z-slab -> L2 locality, no cross-XCD duplicate fetch.
    int bid = blockIdx.x;
    int swz = (bid % NXCD) * (BLOCKS / NXCD) + bid / NXCD;
    int tid = swz * 256 + (int)threadIdx.x;          // < 8,192,000
    int b = tid / S3I;
    int s = tid % S3I;
    int w = s % S;
    int t = s / S;
    int h = t % S;
    int d = t / S;

    const float* fb = flow + (size_t)b * 3 * S3I;
    float z = (float)d + fb[s];
    float y = (float)h + fb[S3I + s];
    float x = (float)w + fb[2 * S3I + s];

    const float* sb = src + (size_t)b * CH * S3I;
    float r0, r1, r2;

    if (__builtin_expect(*is_msk != 0, 0)) {
        // nearest: round-half-to-even == rintf (default RNE mode)
        int iz = (int)rintf(z), iy = (int)rintf(y), ix = (int)rintf(x);
        bool v = (unsigned)iz < (unsigned)S && (unsigned)iy < (unsigned)S &&
                 (unsigned)ix < (unsigned)S;
        int izc = min(max(iz, 0), S - 1);
        int iyc = min(max(iy, 0), S - 1);
        int ixc = min(max(ix, 0), S - 1);
        int idx = (izc * S + iyc) * S + ixc;
        float m = v ? 1.f : 0.f;
        r0 = m * sb[idx];
        r1 = m * sb[S3I + idx];
        r2 = m * sb[2 * S3I + idx];
    } else {
        // trilinear, zero padding; corner order & weight association match ref.
        float zf = floorf(z), yf = floorf(y), xf = floorf(x);
        float tz = z - zf, ty = y - yf, tx = x - xf;
        int z0 = (int)zf, y0 = (int)yf, x0 = (int)xf;
        int z1 = z0 + 1, y1 = y0 + 1, x1 = x0 + 1;

        int zc0 = min(max(z0, 0), S - 1), zc1 = min(max(z1, 0), S - 1);
        int yc0 = min(max(y0, 0), S - 1), yc1 = min(max(y1, 0), S - 1);
        int xl  = min(max(x0, 0), S - 2);      // 8B window [xl, xl+1] in-bounds

        bool vz0 = (unsigned)z0 < (unsigned)S, vz1 = (unsigned)z1 < (unsigned)S;
        bool vy0 = (unsigned)y0 < (unsigned)S, vy1 = (unsigned)y1 < (unsigned)S;
        bool vx0 = (unsigned)x0 < (unsigned)S, vx1 = (unsigned)x1 < (unsigned)S;

        float wz0 = 1.f - tz, wz1 = tz;
        float wy0 = 1.f - ty, wy1 = ty;
        float wx0 = vx0 ? (1.f - tx) : 0.f;    // x-validity folded into wx
        float wx1 = vx1 ? tx : 0.f;

        float a00 = (vz0 && vy0) ? wz0 * wy0 : 0.f;
        float a01 = (vz0 && vy1) ? wz0 * wy1 : 0.f;
        float a10 = (vz1 && vy0) ? wz1 * wy0 : 0.f;
        float a11 = (vz1 && vy1) ? wz1 * wy1 : 0.f;

        int o00 = (zc0 * S + yc0) * S + xl;
        int o01 = (zc0 * S + yc1) * S + xl;
        int o10 = (zc1 * S + yc0) * S + xl;
        int o11 = (zc1 * S + yc1) * S + xl;

        // value selection per corner (clip semantics):
        //   corner x0: clip(x0) == xl   unless x0 > xl (i.e. x0 == S-1) -> .b
        //   corner x1: clip(x1) == xl+1 unless x1 <= xl (i.e. x1 <= 0)  -> .a
        bool sA = (x0 > xl);
        bool sB = (x1 <= xl);

        // per-corner weights (== ((wz*wy)*wx), ref association)
        float w00A = a00 * wx0, w00B = a00 * wx1;
        float w01A = a01 * wx0, w01B = a01 * wx1;
        float w10A = a10 * wx0, w10B = a10 * wx1;
        float w11A = a11 * wx0, w11B = a11 * wx1;

        float racc[3];
        #pragma unroll
        for (int c = 0; c < 3; ++c) {
            const float* sc = sb + (size_t)c * S3I;
            F2 f00 = *(const F2*)(sc + o00);
            F2 f01 = *(const F2*)(sc + o01);
            F2 f10 = *(const F2*)(sc + o10);
            F2 f11 = *(const F2*)(sc + o11);
            float v, acc;
            v = sA ? f00.b : f00.a;  acc  = w00A * v;
            v = sB ? f00.a : f00.b;  acc += w00B * v;
            v = sA ? f01.b : f01.a;  acc += w01A * v;
            v = sB ? f01.a : f01.b;  acc += w01B * v;
            v = sA ? f10.b : f10.a;  acc += w10A * v;
            v = sB ? f10.a : f10.b;  acc += w10B * v;
            v = sA ? f11.b : f11.a;  acc += w11A * v;
            v = sB ? f11.a : f11.b;  acc += w11B * v;
            racc[c] = acc;
        }
        r0 = racc[0]; r1 = racc[1]; r2 = racc[2];
    }

    float* ob = out + (size_t)b * CH * S3I;
    ob[s]           = r0;
    ob[S3I + s]     = r1;
    ob[2 * S3I + s] = r2;
}

extern "C" void kernel_launch(void* const* d_in, const int* in_sizes, int n_in,
                              void* d_out, int out_size, void* d_ws, size_t ws_size,
                              hipStream_t stream) {
    const float* src    = (const float*)d_in[0];
    const float* flow   = (const float*)d_in[1];
    const int*   is_msk = (const int*)d_in[2];
    float*       out    = (float*)d_out;

    st3d_kernel<<<BLOCKS, 256, 0, stream>>>(src, flow, is_msk, out);
}